// Round 13
// baseline (311.541 us; speedup 1.0000x reference)
//
#include <hip/hip_runtime.h>
#include <hip/hip_bf16.h>
#include <math.h>

#define NTOT  8192
#define DIM   512
#define BATCH (NTOT/2)
#define TEMP_INV 5.0f   // 1/0.2
#define TTILE 64                      // 8192 / 128 tiles per side
#define NBLK  (TTILE*(TTILE+1)/2)     // 2080 upper-triangle tiles
#define GCH   32                      // gram K-chunks (256 samples each)

typedef __attribute__((ext_vector_type(8))) short bf16x8;
typedef __attribute__((ext_vector_type(4))) float f32x4;

__device__ __forceinline__ float b2f(unsigned short u)
{
    unsigned int x = (unsigned int)u << 16;
    float f; __builtin_memcpy(&f, &x, 4); return f;
}

// column-major triangle decode: t = bj*(bj+1)/2 + bi, bi <= bj.
__device__ __forceinline__ void decode_tile(int t, int& bi, int& bj)
{
    int b = (int)((sqrtf(8.0f * (float)t + 1.0f) - 1.0f) * 0.5f);
    while ((b + 1) * (b + 2) / 2 <= t) ++b;
    while (b * (b + 1) / 2 > t)       --b;
    bj = b;
    bi = t - b * (b + 1) / 2;
}

__device__ __forceinline__ unsigned int pack_bf16_2(float a, float b)
{
    __hip_bfloat16 ha = __float2bfloat16(a), hb = __float2bfloat16(b);
    unsigned short ua, ub;
    __builtin_memcpy(&ua, &ha, 2); __builtin_memcpy(&ub, &hb, 2);
    return (unsigned int)ua | ((unsigned int)ub << 16);
}

// ---------------- normalize: one wave per row ----------------
__global__ __launch_bounds__(256)
void normalize_k(const float* __restrict__ z, __hip_bfloat16* __restrict__ zn)
{
    const int lane = threadIdx.x & 63, wave = threadIdx.x >> 6;
    const int row  = blockIdx.x * 4 + wave;
    const float4* zr = (const float4*)(z + (size_t)row * DIM);
    const float4 a = zr[lane];
    const float4 b = zr[lane + 64];
    float ss = a.x*a.x + a.y*a.y + a.z*a.z + a.w*a.w
             + b.x*b.x + b.y*b.y + b.z*b.z + b.w*b.w;
    #pragma unroll
    for (int off = 1; off < 64; off <<= 1) ss += __shfl_xor(ss, off);
    const float inv = 1.0f / fmaxf(sqrtf(ss), 1e-12f);
    uint2* zo = (uint2*)(zn + (size_t)row * DIM);
    uint2 o0, o1;
    o0.x = pack_bf16_2(a.x * inv, a.y * inv);
    o0.y = pack_bf16_2(a.z * inv, a.w * inv);
    o1.x = pack_bf16_2(b.x * inv, b.y * inv);
    o1.y = pack_bf16_2(b.z * inv, b.w * inv);
    zo[lane]      = o0;
    zo[lane + 64] = o1;
}

// ---------------- transpose zn -> znT [512][8192], fused column sums S ----------------
// LDS XOR-swizzle (col ^= ((row>>3)&7)<<3) kills the 16-way read conflict (917K, R5 PMC).
__global__ __launch_bounds__(256)
void transpose_colsum_k(const __hip_bfloat16* __restrict__ zn,
                        __hip_bfloat16* __restrict__ znT,
                        float* __restrict__ S)
{
    __shared__ unsigned short T[64][72];
    __shared__ float Scol[64];
    const int tid = threadIdx.x;
    const int bs = blockIdx.x & 127;       // sample tile
    const int bd = blockIdx.x >> 7;        // dim tile
    const int s0 = bs * 64, d0 = bd * 64;
    if (tid < 64) Scol[tid] = 0.f;
    const int rr = tid >> 3;
    const int c8 = (tid & 7) * 8;
    float part[8];
    #pragma unroll
    for (int j = 0; j < 8; ++j) part[j] = 0.f;
    #pragma unroll
    for (int h = 0; h < 2; ++h) {
        const int row = rr + h * 32;
        const int Xw = ((row >> 3) & 7) << 3;
        const bf16x8 v = *(const bf16x8*)(zn + (size_t)(s0 + row) * DIM + d0 + c8);
        *(bf16x8*)&T[row][c8 ^ Xw] = v;
        #pragma unroll
        for (int j = 0; j < 8; ++j) part[j] += b2f((unsigned short)v[j]);
    }
    __syncthreads();
    const int Xr = ((c8 >> 3) & 7) << 3;
    #pragma unroll
    for (int h = 0; h < 2; ++h) {
        const int d = rr + h * 32;
        bf16x8 ov;
        #pragma unroll
        for (int j = 0; j < 8; ++j) ov[j] = (short)T[c8 + j][d ^ Xr];
        *(bf16x8*)(znT + (size_t)(d0 + d) * NTOT + s0 + c8) = ov;
    }
    #pragma unroll
    for (int j = 0; j < 8; ++j) atomicAdd(&Scol[c8 + j], part[j]);
    __syncthreads();
    if (tid < 64) atomicAdd(&S[d0 + tid], Scol[tid]);
}

// ---------------- shared MFMA K-loop: 128x128 tile, BK=32, 2-stage ring ----------------
__device__ __forceinline__ void issue4(const __hip_bfloat16* A, int sA,
                                       const __hip_bfloat16* B, int sB,
                                       int gk, unsigned short* Ad, unsigned short* Bd,
                                       int wave, int lane)
{
    const int f_l = lane & 15, q_l = lane >> 4;
    #pragma unroll
    for (int q = 0; q < 2; ++q) {
        const int s = wave * 2 + q;
        const __hip_bfloat16* ga = A + (size_t)(s * 16 + f_l) * sA + gk + q_l * 8;
        const __hip_bfloat16* gb = B + (size_t)(s * 16 + f_l) * sB + gk + q_l * 8;
        __builtin_amdgcn_global_load_lds(
            (const __attribute__((address_space(1))) unsigned int*)ga,
            (__attribute__((address_space(3))) unsigned int*)(Ad + s * 512 + lane * 8),
            16, 0, 0);
        __builtin_amdgcn_global_load_lds(
            (const __attribute__((address_space(1))) unsigned int*)gb,
            (__attribute__((address_space(3))) unsigned int*)(Bd + s * 512 + lane * 8),
            16, 0, 0);
    }
}

// 2-stage ring, depth-2 prefetch, counted vmcnt. Safety: buf[ki&1] is re-targeted
// (for tile ki+2) only after barrier2, which every wave reaches with its ds_reads
// of buf[ki&1] complete (explicit lgkmcnt(0)); so block-wide reads-before-overwrite.
template<int NSTEP>
__device__ __forceinline__ void mm_kloop(const __hip_bfloat16* A, int sA,
                                         const __hip_bfloat16* B, int sB,
                                         unsigned short (*As)[4096],
                                         unsigned short (*Bs)[4096],
                                         f32x4 acc[4][4], int wave, int lane)
{
    const int wr = wave >> 1, wc = wave & 1;
    issue4(A, sA, B, sB, 0,  As[0], Bs[0], wave, lane);
    issue4(A, sA, B, sB, 32, As[1], Bs[1], wave, lane);
    #pragma unroll
    for (int ki = 0; ki < NSTEP; ++ki) {
        // buf[ki&1]'s 4 loads are the oldest outstanding; tile ki+1's 4 stay in flight.
        if (ki < NSTEP - 1) asm volatile("s_waitcnt vmcnt(4)\n\ts_barrier" ::: "memory");
        else                asm volatile("s_waitcnt vmcnt(0)\n\ts_barrier" ::: "memory");
        __builtin_amdgcn_sched_barrier(0);
        const unsigned short* Ap = As[ki & 1];
        const unsigned short* Bp = Bs[ki & 1];
        bf16x8 af[4], bfr[4];
        #pragma unroll
        for (int r = 0; r < 4; ++r)
            af[r] = *(const bf16x8*)(Ap + (wr * 4 + r) * 512 + lane * 8);
        #pragma unroll
        for (int c = 0; c < 4; ++c)
            bfr[c] = *(const bf16x8*)(Bp + (wc * 4 + c) * 512 + lane * 8);
        #pragma unroll
        for (int r = 0; r < 4; ++r)
            #pragma unroll
            for (int c = 0; c < 4; ++c)
                acc[r][c] = __builtin_amdgcn_mfma_f32_16x16x32_bf16(af[r], bfr[c], acc[r][c], 0, 0, 0);
        if (ki + 2 < NSTEP) {
            // all my ds_reads of buf[ki&1] complete; sync block; then re-target it.
            __builtin_amdgcn_sched_barrier(0);
            asm volatile("s_waitcnt lgkmcnt(0)\n\ts_barrier" ::: "memory");
            __builtin_amdgcn_sched_barrier(0);
            issue4(A, sA, B, sB, (ki + 2) * 32, As[ki & 1], Bs[ki & 1], wave, lane);
        }
    }
}

// ---------------- Gram partials: 16 quadrants x GCH chunks, plain contiguous stores ----------------
__global__ __launch_bounds__(256, 4)
void gram_k(const __hip_bfloat16* __restrict__ znT, float* __restrict__ Gpart)
{
    __shared__ unsigned short As[2][4096];
    __shared__ unsigned short Bs[2][4096];
    const int tid = threadIdx.x, wave = tid >> 6, lane = tid & 63;
    const int f_l = lane & 15, q_l = lane >> 4;
    const int t = blockIdx.x >> 5, ch = blockIdx.x & 31;
    const int di = (t >> 2) * 128, dj = (t & 3) * 128;
    const int wr = wave >> 1, wc = wave & 1;
    f32x4 acc[4][4];
    #pragma unroll
    for (int r = 0; r < 4; ++r)
        #pragma unroll
        for (int c = 0; c < 4; ++c) acc[r][c] = (f32x4){0.f, 0.f, 0.f, 0.f};
    mm_kloop<8>(znT + (size_t)di * NTOT + ch * 256, NTOT,
                znT + (size_t)dj * NTOT + ch * 256, NTOT, As, Bs, acc, wave, lane);
    float* gp = Gpart + ((size_t)t * GCH + ch) * 16384;   // contiguous 128x128 slice
    #pragma unroll
    for (int r = 0; r < 4; ++r)
        #pragma unroll
        for (int c = 0; c < 4; ++c)
            #pragma unroll
            for (int u = 0; u < 4; ++u) {
                const int row = wr * 64 + r * 16 + q_l * 4 + u;
                const int col = wc * 64 + c * 16 + f_l;
                gp[row * 128 + col] = acc[r][c][u];
            }
}

// ---------------- reduce GCH partials -> bf16 G (512 blocks, coalesced) ----------------
__global__ __launch_bounds__(256)
void gram_fin_k(const float* __restrict__ Gpart, __hip_bfloat16* __restrict__ G1)
{
    const int t  = blockIdx.x >> 5;            // quadrant
    const int e  = ((blockIdx.x & 31) * 256 + threadIdx.x) * 2;   // elem in quadrant
    const int di = (t >> 2) * 128, dj = (t & 3) * 128;
    const float* qb = Gpart + (size_t)t * GCH * 16384 + e;
    float sx = 0.f, sy = 0.f;
    #pragma unroll
    for (int ch = 0; ch < GCH; ++ch) {
        const float2 v = *(const float2*)(qb + ch * 16384);
        sx += v.x; sy += v.y;
    }
    const int rl = e >> 7, cl = e & 127;
    *(unsigned int*)(G1 + (size_t)(di + rl) * 512 + dj + cl) = pack_bf16_2(sx, sy);
}

// ---------------- rowsumsq partials: 64 R-groups x 4C x 2Kh, 16 per-wave slices (race-free) ----------------
__global__ __launch_bounds__(256, 4)
void rowstats_k(const __hip_bfloat16* __restrict__ zn,
                const __hip_bfloat16* __restrict__ G1,
                float* __restrict__ rsq_part)
{
    __shared__ unsigned short As[2][4096];
    __shared__ unsigned short Bs[2][4096];
    const int tid = threadIdx.x, wave = tid >> 6, lane = tid & 63;
    const int f_l = lane & 15, q_l = lane >> 4;
    const int g  = blockIdx.x >> 3;
    const int R0 = g * 128;
    const int cb = (blockIdx.x >> 1) & 3;
    const int C0 = cb * 128;
    const int khi = blockIdx.x & 1;
    const int kh  = khi * 256;
    const int wr = wave >> 1, wc = wave & 1;
    const int part = ((cb * 2 + khi) << 1) | wc;   // 0..15 — wc included (R7 race fix)
    f32x4 acc[4][4];
    #pragma unroll
    for (int r = 0; r < 4; ++r)
        #pragma unroll
        for (int c = 0; c < 4; ++c) acc[r][c] = (f32x4){0.f, 0.f, 0.f, 0.f};
    mm_kloop<8>(zn + (size_t)R0 * DIM + kh, DIM, G1 + (size_t)C0 * DIM + kh, DIM,
                As, Bs, acc, wave, lane);
    #pragma unroll
    for (int r = 0; r < 4; ++r) {
        float4 pv;
        #pragma unroll
        for (int u = 0; u < 4; ++u) {
            const int i = R0 + wr * 64 + r * 16 + q_l * 4 + u;
            float p = 0.f;
            #pragma unroll
            for (int c = 0; c < 4; ++c) {
                const int col = C0 + wc * 64 + c * 16 + f_l;
                unsigned short zb;
                __builtin_memcpy(&zb, zn + (size_t)i * DIM + col, 2);
                p += acc[r][c][u] * b2f(zb);
            }
            p += __shfl_xor(p, 1); p += __shfl_xor(p, 2);
            p += __shfl_xor(p, 4); p += __shfl_xor(p, 8);
            ((float*)&pv)[u] = p;
        }
        if (f_l == 0)
            *(float4*)(rsq_part + (size_t)part * NTOT + R0 + wr * 64 + r * 16 + q_l * 4) = pv;
    }
}

// ---------------- finalize stats (rowsum = zn_i.S, sum 16 rsq partials) + positive pairs ----------------
__global__ __launch_bounds__(256)
void finalize_pos_k(const __hip_bfloat16* __restrict__ zn,
                    const float* __restrict__ S,
                    const float* __restrict__ rsq_part,
                    const int* __restrict__ labels,
                    float* __restrict__ mu_d,
                    float* __restrict__ inv2s2,
                    double* __restrict__ pos_acc)
{
    const int lane = threadIdx.x & 63, wave = threadIdx.x >> 6;
    const int row = blockIdx.x * 4 + wave;
    const bf16x8 v = *(const bf16x8*)(zn + (size_t)row * DIM + lane * 8);
    const float4 sa = *(const float4*)(S + lane * 8);
    const float4 sb = *(const float4*)(S + lane * 8 + 4);
    float acc = b2f((unsigned short)v[0]) * sa.x + b2f((unsigned short)v[1]) * sa.y
              + b2f((unsigned short)v[2]) * sa.z + b2f((unsigned short)v[3]) * sa.w
              + b2f((unsigned short)v[4]) * sb.x + b2f((unsigned short)v[5]) * sb.y
              + b2f((unsigned short)v[6]) * sb.z + b2f((unsigned short)v[7]) * sb.w;
    float vp = 0.f;
    if (row < BATCH) {
        const bf16x8 w = *(const bf16x8*)(zn + (size_t)(row + BATCH) * DIM + lane * 8);
        #pragma unroll
        for (int j = 0; j < 8; ++j)
            vp += b2f((unsigned short)v[j]) * b2f((unsigned short)w[j]);
    }
    #pragma unroll
    for (int off = 1; off < 64; off <<= 1) {
        acc += __shfl_xor(acc, off);
        vp  += __shfl_xor(vp, off);
    }
    if (lane == 0) {
        float sq = 0.f;
        #pragma unroll
        for (int p = 0; p < 16; ++p) sq += rsq_part[(size_t)p * NTOT + row];
        const float s = acc;
        const float mean_sim = s * (1.0f / NTOT);
        const float var = (sq - s * mean_sim) * (1.0f / (NTOT - 1));
        mu_d[row]   = 1.0f - mean_sim;
        inv2s2[row] = 1.0f / (2.0f * var);
        if (row < BATCH && labels[row] == labels[row + BATCH])
            atomicAdd(pos_acc, (double)__expf(vp * TEMP_INV));
    }
}

// ---------------- fused triangle GEMM + exp epilogue (2-ring, 5 blocks/CU, LDS=32KB exact) ----------------
__global__ __launch_bounds__(256, 5)
void sim_neg_k(const __hip_bfloat16* __restrict__ zn,
               const int*   __restrict__ labels,
               const float* __restrict__ mu_d,
               const float* __restrict__ inv2s2,
               double* __restrict__ neg_acc)
{
    __shared__ unsigned short As[2][4096];
    __shared__ unsigned short Bs[2][4096];
    // redbuf overlaid on As[0]: safe — epilogue runs after the ki=15 barrier, by which
    // point all ring[0] reads (last at ki=14) and DMA writes (last issued ki=12,
    // drained by vmcnt(0)) are complete block-wide. Keeps LDS at exactly 32768 B
    // so 5 blocks/CU fit (5 x 32768 = 163840 = 160 KiB exactly).
    float* redbuf = (float*)As[0];
    const int tid = threadIdx.x, wave = tid >> 6, lane = tid & 63;
    const int f_l = lane & 15, q_l = lane >> 4;
    int bi, bj;
    decode_tile(blockIdx.x, bi, bj);
    const int R0 = bi * 128, C0 = bj * 128;
    const int wr = wave >> 1, wc = wave & 1;
    f32x4 acc[4][4];
    #pragma unroll
    for (int r = 0; r < 4; ++r)
        #pragma unroll
        for (int c = 0; c < 4; ++c) acc[r][c] = (f32x4){0.f, 0.f, 0.f, 0.f};
    mm_kloop<16>(zn + (size_t)R0 * DIM, DIM, zn + (size_t)C0 * DIM, DIM, As, Bs, acc, wave, lane);

    int labj[4]; float muj[4], isj[4];
    #pragma unroll
    for (int c = 0; c < 4; ++c) {
        const int j = C0 + wc * 64 + c * 16 + f_l;
        labj[c] = labels[j]; muj[c] = mu_d[j]; isj[c] = inv2s2[j];
    }
    float local = 0.f;
    #pragma unroll
    for (int r = 0; r < 4; ++r) {
        const int ib = R0 + wr * 64 + r * 16 + q_l * 4;
        #pragma unroll
        for (int u = 0; u < 4; ++u) {
            const int   li = labels[ib + u];
            const float mi = mu_d[ib + u];
            const float vi = inv2s2[ib + u];
            #pragma unroll
            for (int c = 0; c < 4; ++c) {
                const float s  = acc[r][c][u];
                const float dj = (1.0f - s) - muj[c];
                float e = __expf(s * TEMP_INV + dj * dj * isj[c]);
                if (bi != bj) {
                    const float di = (1.0f - s) - mi;
                    e += __expf(s * TEMP_INV + di * di * vi);
                }
                local += (li != labj[c]) ? e : 0.f;
            }
        }
    }
    #pragma unroll
    for (int off = 1; off < 64; off <<= 1) local += __shfl_xor(local, off);
    __syncthreads();                       // all waves past kloop before LDS reuse
    if (lane == 0) redbuf[wave] = local;
    __syncthreads();
    if (tid == 0)
        atomicAdd(neg_acc, (double)(redbuf[0] + redbuf[1] + redbuf[2] + redbuf[3]));
}

// ---------------- final loss ----------------
__global__ void loss_k(const double* __restrict__ accs, float* __restrict__ out)
{
    const double neg = accs[0], pos = accs[1];
    out[0] = (float)(-log(pos / (pos + neg)));
}

extern "C" void kernel_launch(void* const* d_in, const int* in_sizes, int n_in,
                              void* d_out, int out_size, void* d_ws, size_t ws_size,
                              hipStream_t stream)
{
    const float* z      = (const float*)d_in[0];
    const int*   labels = (const int*)d_in[1];
    float* out = (float*)d_out;

    char* ws = (char*)d_ws;
    __hip_bfloat16* zn  = (__hip_bfloat16*)ws;                        // 8 MiB
    __hip_bfloat16* znT = (__hip_bfloat16*)(ws + ((size_t)8 << 20));  // 8 MiB
    float* Gpart        = (float*)(ws + ((size_t)16 << 20));          // 32 MiB
    char* tail          = ws + ((size_t)48 << 20);
    float*  S        = (float*)tail;                                  // 512 f
    double* accs     = (double*)(S + 512);                            // [0]=neg [1]=pos
    float*  rsq_part = (float*)(accs + 2);                            // 16 x 8192 f
    float*  mu_d     = rsq_part + 16 * NTOT;                          // 8192 f
    float*  inv2s2   = mu_d + NTOT;                                   // 8192 f
    __hip_bfloat16* G1 = (__hip_bfloat16*)(inv2s2 + NTOT);            // 512 KiB

    // zero: S + accs only (all partials are fully overwritten by plain stores)
    (void)hipMemsetAsync(S, 0, 512 * sizeof(float) + 2 * sizeof(double), stream);

    normalize_k<<<NTOT / 4, 256, 0, stream>>>(z, zn);
    transpose_colsum_k<<<1024, 256, 0, stream>>>(zn, znT, S);
    gram_k<<<16 * GCH, 256, 0, stream>>>(znT, Gpart);
    gram_fin_k<<<512, 256, 0, stream>>>(Gpart, G1);
    rowstats_k<<<512, 256, 0, stream>>>(zn, G1, rsq_part);
    finalize_pos_k<<<NTOT / 4, 256, 0, stream>>>(zn, S, rsq_part, labels, mu_d, inv2s2, accs + 1);
    sim_neg_k<<<NBLK, 256, 0, stream>>>(zn, labels, mu_d, inv2s2, accs);
    loss_k<<<1, 1, 0, stream>>>(accs, out);
}

// Round 14
// 202.318 us; speedup vs baseline: 1.5399x; 1.5399x over previous
//
#include <hip/hip_runtime.h>
#include <hip/hip_bf16.h>
#include <math.h>

#define NTOT  8192
#define DIM   512
#define BATCH (NTOT/2)
#define TEMP_INV 5.0f   // 1/0.2
#define TTILE 64                      // 8192 / 128 tiles per side
#define NBLK  (TTILE*(TTILE+1)/2)     // 2080 upper-triangle tiles
#define GCH   32                      // gram K-chunks (256 samples each)

typedef __attribute__((ext_vector_type(8))) short bf16x8;
typedef __attribute__((ext_vector_type(4))) float f32x4;

__device__ __forceinline__ float b2f(unsigned short u)
{
    unsigned int x = (unsigned int)u << 16;
    float f; __builtin_memcpy(&f, &x, 4); return f;
}

// column-major triangle decode: t = bj*(bj+1)/2 + bi, bi <= bj.
__device__ __forceinline__ void decode_tile(int t, int& bi, int& bj)
{
    int b = (int)((sqrtf(8.0f * (float)t + 1.0f) - 1.0f) * 0.5f);
    while ((b + 1) * (b + 2) / 2 <= t) ++b;
    while (b * (b + 1) / 2 > t)       --b;
    bj = b;
    bi = t - b * (b + 1) / 2;
}

__device__ __forceinline__ unsigned int pack_bf16_2(float a, float b)
{
    __hip_bfloat16 ha = __float2bfloat16(a), hb = __float2bfloat16(b);
    unsigned short ua, ub;
    __builtin_memcpy(&ua, &ha, 2); __builtin_memcpy(&ub, &hb, 2);
    return (unsigned int)ua | ((unsigned int)ub << 16);
}

// ---------------- normalize: one wave per row ----------------
__global__ __launch_bounds__(256)
void normalize_k(const float* __restrict__ z, __hip_bfloat16* __restrict__ zn)
{
    const int lane = threadIdx.x & 63, wave = threadIdx.x >> 6;
    const int row  = blockIdx.x * 4 + wave;
    const float4* zr = (const float4*)(z + (size_t)row * DIM);
    const float4 a = zr[lane];
    const float4 b = zr[lane + 64];
    float ss = a.x*a.x + a.y*a.y + a.z*a.z + a.w*a.w
             + b.x*b.x + b.y*b.y + b.z*b.z + b.w*b.w;
    #pragma unroll
    for (int off = 1; off < 64; off <<= 1) ss += __shfl_xor(ss, off);
    const float inv = 1.0f / fmaxf(sqrtf(ss), 1e-12f);
    uint2* zo = (uint2*)(zn + (size_t)row * DIM);
    uint2 o0, o1;
    o0.x = pack_bf16_2(a.x * inv, a.y * inv);
    o0.y = pack_bf16_2(a.z * inv, a.w * inv);
    o1.x = pack_bf16_2(b.x * inv, b.y * inv);
    o1.y = pack_bf16_2(b.z * inv, b.w * inv);
    zo[lane]      = o0;
    zo[lane + 64] = o1;
}

// ---------------- transpose zn -> znT [512][8192], fused column sums S ----------------
// LDS XOR-swizzle (col ^= ((row>>3)&7)<<3) kills the 16-way read conflict (917K, R5 PMC).
__global__ __launch_bounds__(256)
void transpose_colsum_k(const __hip_bfloat16* __restrict__ zn,
                        __hip_bfloat16* __restrict__ znT,
                        float* __restrict__ S)
{
    __shared__ unsigned short T[64][72];
    __shared__ float Scol[64];
    const int tid = threadIdx.x;
    const int bs = blockIdx.x & 127;       // sample tile
    const int bd = blockIdx.x >> 7;        // dim tile
    const int s0 = bs * 64, d0 = bd * 64;
    if (tid < 64) Scol[tid] = 0.f;
    const int rr = tid >> 3;
    const int c8 = (tid & 7) * 8;
    float part[8];
    #pragma unroll
    for (int j = 0; j < 8; ++j) part[j] = 0.f;
    #pragma unroll
    for (int h = 0; h < 2; ++h) {
        const int row = rr + h * 32;
        const int Xw = ((row >> 3) & 7) << 3;
        const bf16x8 v = *(const bf16x8*)(zn + (size_t)(s0 + row) * DIM + d0 + c8);
        *(bf16x8*)&T[row][c8 ^ Xw] = v;
        #pragma unroll
        for (int j = 0; j < 8; ++j) part[j] += b2f((unsigned short)v[j]);
    }
    __syncthreads();
    const int Xr = ((c8 >> 3) & 7) << 3;
    #pragma unroll
    for (int h = 0; h < 2; ++h) {
        const int d = rr + h * 32;
        bf16x8 ov;
        #pragma unroll
        for (int j = 0; j < 8; ++j) ov[j] = (short)T[c8 + j][d ^ Xr];
        *(bf16x8*)(znT + (size_t)(d0 + d) * NTOT + s0 + c8) = ov;
    }
    #pragma unroll
    for (int j = 0; j < 8; ++j) atomicAdd(&Scol[c8 + j], part[j]);
    __syncthreads();
    if (tid < 64) atomicAdd(&S[d0 + tid], Scol[tid]);
}

// ---------------- shared MFMA K-loop: 128x128 tile, BK=32, 2-stage ring ----------------
__device__ __forceinline__ void issue4(const __hip_bfloat16* A, int sA,
                                       const __hip_bfloat16* B, int sB,
                                       int gk, unsigned short* Ad, unsigned short* Bd,
                                       int wave, int lane)
{
    const int f_l = lane & 15, q_l = lane >> 4;
    #pragma unroll
    for (int q = 0; q < 2; ++q) {
        const int s = wave * 2 + q;
        const __hip_bfloat16* ga = A + (size_t)(s * 16 + f_l) * sA + gk + q_l * 8;
        const __hip_bfloat16* gb = B + (size_t)(s * 16 + f_l) * sB + gk + q_l * 8;
        __builtin_amdgcn_global_load_lds(
            (const __attribute__((address_space(1))) unsigned int*)ga,
            (__attribute__((address_space(3))) unsigned int*)(Ad + s * 512 + lane * 8),
            16, 0, 0);
        __builtin_amdgcn_global_load_lds(
            (const __attribute__((address_space(1))) unsigned int*)gb,
            (__attribute__((address_space(3))) unsigned int*)(Bd + s * 512 + lane * 8),
            16, 0, 0);
    }
}

// 2-stage ring, depth-2 prefetch, counted vmcnt. Safety: buf[ki&1] is re-targeted
// (for tile ki+2) only after barrier2, which every wave reaches with its ds_reads
// of buf[ki&1] complete (explicit lgkmcnt(0)); so block-wide reads-before-overwrite.
template<int NSTEP>
__device__ __forceinline__ void mm_kloop(const __hip_bfloat16* A, int sA,
                                         const __hip_bfloat16* B, int sB,
                                         unsigned short (*As)[4096],
                                         unsigned short (*Bs)[4096],
                                         f32x4 acc[4][4], int wave, int lane)
{
    const int wr = wave >> 1, wc = wave & 1;
    issue4(A, sA, B, sB, 0,  As[0], Bs[0], wave, lane);
    issue4(A, sA, B, sB, 32, As[1], Bs[1], wave, lane);
    #pragma unroll
    for (int ki = 0; ki < NSTEP; ++ki) {
        // buf[ki&1]'s 4 loads are the oldest outstanding; tile ki+1's 4 stay in flight.
        if (ki < NSTEP - 1) asm volatile("s_waitcnt vmcnt(4)\n\ts_barrier" ::: "memory");
        else                asm volatile("s_waitcnt vmcnt(0)\n\ts_barrier" ::: "memory");
        __builtin_amdgcn_sched_barrier(0);
        const unsigned short* Ap = As[ki & 1];
        const unsigned short* Bp = Bs[ki & 1];
        bf16x8 af[4], bfr[4];
        #pragma unroll
        for (int r = 0; r < 4; ++r)
            af[r] = *(const bf16x8*)(Ap + (wr * 4 + r) * 512 + lane * 8);
        #pragma unroll
        for (int c = 0; c < 4; ++c)
            bfr[c] = *(const bf16x8*)(Bp + (wc * 4 + c) * 512 + lane * 8);
        #pragma unroll
        for (int r = 0; r < 4; ++r)
            #pragma unroll
            for (int c = 0; c < 4; ++c)
                acc[r][c] = __builtin_amdgcn_mfma_f32_16x16x32_bf16(af[r], bfr[c], acc[r][c], 0, 0, 0);
        if (ki + 2 < NSTEP) {
            // all my ds_reads of buf[ki&1] complete; sync block; then re-target it.
            __builtin_amdgcn_sched_barrier(0);
            asm volatile("s_waitcnt lgkmcnt(0)\n\ts_barrier" ::: "memory");
            __builtin_amdgcn_sched_barrier(0);
            issue4(A, sA, B, sB, (ki + 2) * 32, As[ki & 1], Bs[ki & 1], wave, lane);
        }
    }
}

// ---------------- Gram partials: 16 quadrants x GCH chunks, plain contiguous stores ----------------
__global__ __launch_bounds__(256, 4)
void gram_k(const __hip_bfloat16* __restrict__ znT, float* __restrict__ Gpart)
{
    __shared__ unsigned short As[2][4096];
    __shared__ unsigned short Bs[2][4096];
    const int tid = threadIdx.x, wave = tid >> 6, lane = tid & 63;
    const int f_l = lane & 15, q_l = lane >> 4;
    const int t = blockIdx.x >> 5, ch = blockIdx.x & 31;
    const int di = (t >> 2) * 128, dj = (t & 3) * 128;
    const int wr = wave >> 1, wc = wave & 1;
    f32x4 acc[4][4];
    #pragma unroll
    for (int r = 0; r < 4; ++r)
        #pragma unroll
        for (int c = 0; c < 4; ++c) acc[r][c] = (f32x4){0.f, 0.f, 0.f, 0.f};
    mm_kloop<8>(znT + (size_t)di * NTOT + ch * 256, NTOT,
                znT + (size_t)dj * NTOT + ch * 256, NTOT, As, Bs, acc, wave, lane);
    float* gp = Gpart + ((size_t)t * GCH + ch) * 16384;   // contiguous 128x128 slice
    #pragma unroll
    for (int r = 0; r < 4; ++r)
        #pragma unroll
        for (int c = 0; c < 4; ++c)
            #pragma unroll
            for (int u = 0; u < 4; ++u) {
                const int row = wr * 64 + r * 16 + q_l * 4 + u;
                const int col = wc * 64 + c * 16 + f_l;
                gp[row * 128 + col] = acc[r][c][u];
            }
}

// ---------------- reduce GCH partials -> bf16 G (512 blocks, coalesced) ----------------
__global__ __launch_bounds__(256)
void gram_fin_k(const float* __restrict__ Gpart, __hip_bfloat16* __restrict__ G1)
{
    const int t  = blockIdx.x >> 5;            // quadrant
    const int e  = ((blockIdx.x & 31) * 256 + threadIdx.x) * 2;   // elem in quadrant
    const int di = (t >> 2) * 128, dj = (t & 3) * 128;
    const float* qb = Gpart + (size_t)t * GCH * 16384 + e;
    float sx = 0.f, sy = 0.f;
    #pragma unroll
    for (int ch = 0; ch < GCH; ++ch) {
        const float2 v = *(const float2*)(qb + ch * 16384);
        sx += v.x; sy += v.y;
    }
    const int rl = e >> 7, cl = e & 127;
    *(unsigned int*)(G1 + (size_t)(di + rl) * 512 + dj + cl) = pack_bf16_2(sx, sy);
}

// ---------------- rowsumsq partials: 64 R-groups x 4C x 2Kh, 16 per-wave slices (race-free) ----------------
__global__ __launch_bounds__(256, 4)
void rowstats_k(const __hip_bfloat16* __restrict__ zn,
                const __hip_bfloat16* __restrict__ G1,
                float* __restrict__ rsq_part)
{
    __shared__ unsigned short As[2][4096];
    __shared__ unsigned short Bs[2][4096];
    const int tid = threadIdx.x, wave = tid >> 6, lane = tid & 63;
    const int f_l = lane & 15, q_l = lane >> 4;
    const int g  = blockIdx.x >> 3;
    const int R0 = g * 128;
    const int cb = (blockIdx.x >> 1) & 3;
    const int C0 = cb * 128;
    const int khi = blockIdx.x & 1;
    const int kh  = khi * 256;
    const int wr = wave >> 1, wc = wave & 1;
    const int part = ((cb * 2 + khi) << 1) | wc;   // 0..15 — wc included (R7 race fix)
    f32x4 acc[4][4];
    #pragma unroll
    for (int r = 0; r < 4; ++r)
        #pragma unroll
        for (int c = 0; c < 4; ++c) acc[r][c] = (f32x4){0.f, 0.f, 0.f, 0.f};
    mm_kloop<8>(zn + (size_t)R0 * DIM + kh, DIM, G1 + (size_t)C0 * DIM + kh, DIM,
                As, Bs, acc, wave, lane);
    #pragma unroll
    for (int r = 0; r < 4; ++r) {
        float4 pv;
        #pragma unroll
        for (int u = 0; u < 4; ++u) {
            const int i = R0 + wr * 64 + r * 16 + q_l * 4 + u;
            float p = 0.f;
            #pragma unroll
            for (int c = 0; c < 4; ++c) {
                const int col = C0 + wc * 64 + c * 16 + f_l;
                unsigned short zb;
                __builtin_memcpy(&zb, zn + (size_t)i * DIM + col, 2);
                p += acc[r][c][u] * b2f(zb);
            }
            p += __shfl_xor(p, 1); p += __shfl_xor(p, 2);
            p += __shfl_xor(p, 4); p += __shfl_xor(p, 8);
            ((float*)&pv)[u] = p;
        }
        if (f_l == 0)
            *(float4*)(rsq_part + (size_t)part * NTOT + R0 + wr * 64 + r * 16 + q_l * 4) = pv;
    }
}

// ---------------- finalize stats (rowsum = zn_i.S, sum 16 rsq partials) + positive pairs ----------------
__global__ __launch_bounds__(256)
void finalize_pos_k(const __hip_bfloat16* __restrict__ zn,
                    const float* __restrict__ S,
                    const float* __restrict__ rsq_part,
                    const int* __restrict__ labels,
                    float* __restrict__ mu_d,
                    float* __restrict__ inv2s2,
                    double* __restrict__ pos_acc)
{
    const int lane = threadIdx.x & 63, wave = threadIdx.x >> 6;
    const int row = blockIdx.x * 4 + wave;
    const bf16x8 v = *(const bf16x8*)(zn + (size_t)row * DIM + lane * 8);
    const float4 sa = *(const float4*)(S + lane * 8);
    const float4 sb = *(const float4*)(S + lane * 8 + 4);
    float acc = b2f((unsigned short)v[0]) * sa.x + b2f((unsigned short)v[1]) * sa.y
              + b2f((unsigned short)v[2]) * sa.z + b2f((unsigned short)v[3]) * sa.w
              + b2f((unsigned short)v[4]) * sb.x + b2f((unsigned short)v[5]) * sb.y
              + b2f((unsigned short)v[6]) * sb.z + b2f((unsigned short)v[7]) * sb.w;
    float vp = 0.f;
    if (row < BATCH) {
        const bf16x8 w = *(const bf16x8*)(zn + (size_t)(row + BATCH) * DIM + lane * 8);
        #pragma unroll
        for (int j = 0; j < 8; ++j)
            vp += b2f((unsigned short)v[j]) * b2f((unsigned short)w[j]);
    }
    #pragma unroll
    for (int off = 1; off < 64; off <<= 1) {
        acc += __shfl_xor(acc, off);
        vp  += __shfl_xor(vp, off);
    }
    if (lane == 0) {
        float sq = 0.f;
        #pragma unroll
        for (int p = 0; p < 16; ++p) sq += rsq_part[(size_t)p * NTOT + row];
        const float s = acc;
        const float mean_sim = s * (1.0f / NTOT);
        const float var = (sq - s * mean_sim) * (1.0f / (NTOT - 1));
        mu_d[row]   = 1.0f - mean_sim;
        inv2s2[row] = 1.0f / (2.0f * var);
        if (row < BATCH && labels[row] == labels[row + BATCH])
            atomicAdd(pos_acc, (double)__expf(vp * TEMP_INV));
    }
}

// ---------------- fused triangle GEMM + exp epilogue ----------------
// launch_bounds (256,4): proven codegen (VGPR 64, no spill). LDS shrunk to exactly
// 32768 B via redbuf overlay on As[0] -> HW LDS limit allows 5 blocks/CU
// (5 x 32768 = 160 KiB exactly); VGPR 64 allows 8. Residency = 5.
__global__ __launch_bounds__(256, 4)
void sim_neg_k(const __hip_bfloat16* __restrict__ zn,
               const int*   __restrict__ labels,
               const float* __restrict__ mu_d,
               const float* __restrict__ inv2s2,
               double* __restrict__ neg_acc)
{
    __shared__ unsigned short As[2][4096];
    __shared__ unsigned short Bs[2][4096];
    // redbuf overlaid on As[0]: safe — epilogue runs after the ki=15 barrier, by which
    // point all ring reads and DMA writes are complete block-wide (vmcnt(0) drain),
    // and an explicit __syncthreads precedes the overlay write.
    float* redbuf = (float*)As[0];
    const int tid = threadIdx.x, wave = tid >> 6, lane = tid & 63;
    const int f_l = lane & 15, q_l = lane >> 4;
    int bi, bj;
    decode_tile(blockIdx.x, bi, bj);
    const int R0 = bi * 128, C0 = bj * 128;
    const int wr = wave >> 1, wc = wave & 1;
    f32x4 acc[4][4];
    #pragma unroll
    for (int r = 0; r < 4; ++r)
        #pragma unroll
        for (int c = 0; c < 4; ++c) acc[r][c] = (f32x4){0.f, 0.f, 0.f, 0.f};
    mm_kloop<16>(zn + (size_t)R0 * DIM, DIM, zn + (size_t)C0 * DIM, DIM, As, Bs, acc, wave, lane);

    int labj[4]; float muj[4], isj[4];
    #pragma unroll
    for (int c = 0; c < 4; ++c) {
        const int j = C0 + wc * 64 + c * 16 + f_l;
        labj[c] = labels[j]; muj[c] = mu_d[j]; isj[c] = inv2s2[j];
    }
    float local = 0.f;
    #pragma unroll
    for (int r = 0; r < 4; ++r) {
        const int ib = R0 + wr * 64 + r * 16 + q_l * 4;
        #pragma unroll
        for (int u = 0; u < 4; ++u) {
            const int   li = labels[ib + u];
            const float mi = mu_d[ib + u];
            const float vi = inv2s2[ib + u];
            #pragma unroll
            for (int c = 0; c < 4; ++c) {
                const float s  = acc[r][c][u];
                const float dj = (1.0f - s) - muj[c];
                float e = __expf(s * TEMP_INV + dj * dj * isj[c]);
                if (bi != bj) {
                    const float di = (1.0f - s) - mi;
                    e += __expf(s * TEMP_INV + di * di * vi);
                }
                local += (li != labj[c]) ? e : 0.f;
            }
        }
    }
    #pragma unroll
    for (int off = 1; off < 64; off <<= 1) local += __shfl_xor(local, off);
    __syncthreads();                       // all waves past kloop before LDS reuse
    if (lane == 0) redbuf[wave] = local;
    __syncthreads();
    if (tid == 0)
        atomicAdd(neg_acc, (double)(redbuf[0] + redbuf[1] + redbuf[2] + redbuf[3]));
}

// ---------------- final loss ----------------
__global__ void loss_k(const double* __restrict__ accs, float* __restrict__ out)
{
    const double neg = accs[0], pos = accs[1];
    out[0] = (float)(-log(pos / (pos + neg)));
}

extern "C" void kernel_launch(void* const* d_in, const int* in_sizes, int n_in,
                              void* d_out, int out_size, void* d_ws, size_t ws_size,
                              hipStream_t stream)
{
    const float* z      = (const float*)d_in[0];
    const int*   labels = (const int*)d_in[1];
    float* out = (float*)d_out;

    char* ws = (char*)d_ws;
    __hip_bfloat16* zn  = (__hip_bfloat16*)ws;                        // 8 MiB
    __hip_bfloat16* znT = (__hip_bfloat16*)(ws + ((size_t)8 << 20));  // 8 MiB
    float* Gpart        = (float*)(ws + ((size_t)16 << 20));          // 32 MiB
    char* tail          = ws + ((size_t)48 << 20);
    float*  S        = (float*)tail;                                  // 512 f
    double* accs     = (double*)(S + 512);                            // [0]=neg [1]=pos
    float*  rsq_part = (float*)(accs + 2);                            // 16 x 8192 f
    float*  mu_d     = rsq_part + 16 * NTOT;                          // 8192 f
    float*  inv2s2   = mu_d + NTOT;                                   // 8192 f
    __hip_bfloat16* G1 = (__hip_bfloat16*)(inv2s2 + NTOT);            // 512 KiB

    // zero: S + accs only (all partials are fully overwritten by plain stores)
    (void)hipMemsetAsync(S, 0, 512 * sizeof(float) + 2 * sizeof(double), stream);

    normalize_k<<<NTOT / 4, 256, 0, stream>>>(z, zn);
    transpose_colsum_k<<<1024, 256, 0, stream>>>(zn, znT, S);
    gram_k<<<16 * GCH, 256, 0, stream>>>(znT, Gpart);
    gram_fin_k<<<512, 256, 0, stream>>>(Gpart, G1);
    rowstats_k<<<512, 256, 0, stream>>>(zn, G1, rsq_part);
    finalize_pos_k<<<NTOT / 4, 256, 0, stream>>>(zn, S, rsq_part, labels, mu_d, inv2s2, accs + 1);
    sim_neg_k<<<NBLK, 256, 0, stream>>>(zn, labels, mu_d, inv2s2, accs);
    loss_k<<<1, 1, 0, stream>>>(accs, out);
}